// Round 3
// baseline (244.561 us; speedup 1.0000x reference)
//
#include <hip/hip_runtime.h>
#include <hip/hip_cooperative_groups.h>
#include <float.h>

namespace cg = cooperative_groups;

// Problem constants (from reference setup_inputs)
#define B_SZ 2
#define N_SZ 16384                  // N == M
#define E_SZ 49152

#define GRID 256                    // 1 block/CU, cooperative (co-residency guaranteed)
#define TPB 512
#define WAVES (TPB / 64)            // 8
#define REPS 2                      // rep == dir; 256 blocks x 2 reps = 512 chamfer tiles
#define ROWS_PER_BLOCK 128          // 2 row-pairs x 64 rows; 4 col-groups
#define CHUNK 1024                  // target points per LDS chunk
#define NCHUNK (N_SZ / CHUNK)       // 16
#define TILES_PER_CHUNK (CHUNK / 32) // 32
#define TILES_PER_CG (TILES_PER_CHUNK / 4) // 8 col-tiles per col-group

// frag workspace: per dir, per batch: plane0 [16384 x 16B] then plane1
#define PLANE_BYTES (N_SZ * 16)                 // 256 KB
#define BATCH_FRAG_BYTES (2 * PLANE_BYTES)      // 512 KB
#define DIR_FRAG_BYTES (B_SZ * BATCH_FRAG_BYTES) // 1 MB
#define SUMS_OFF (2 * DIR_FRAG_BYTES)           // 2 MB

typedef short short8 __attribute__((ext_vector_type(8)));
typedef float f32x16 __attribute__((ext_vector_type(16)));

// ---- bf16 bit helpers (RNE); inputs are finite Gaussians ----
__device__ inline short f2bf(float f) {
    unsigned u = __float_as_uint(f);
    unsigned r = (u + 0x7fffu + ((u >> 16) & 1u)) >> 16;
    return (short)r;
}
__device__ inline float bf2f(short s) {
    return __uint_as_float(((unsigned)(unsigned short)s) << 16);
}

// ---- async global->LDS 16B per lane (CK-style addrspace casts) ----
typedef __attribute__((address_space(1))) const unsigned int g_u32;
typedef __attribute__((address_space(3))) unsigned int l_u32;
__device__ inline void gload_lds16(const void* g, void* l) {
    __builtin_amdgcn_global_load_lds((g_u32*)g, (l_u32*)l, 16, 0, 0);
}

// ---- ONE cooperative kernel: prep | sync | edge + chamfer | sync | final ----
// d^2 = (-2p).t + p^2 + t^2 via K=13 bf16 hi/lo split in ONE 32x32x16 MFMA.
// A lane: m=lane&31, k=(lane>>5)*8+j:
//   half0 (k0-7):  {ahx,ahy,ahz, alx,aly,alz, p2h,p2l}   (a = -2p)
//   half1 (k8-15): {ahx,ahy,ahz, 1, 1, 0,0,0}
// B per point t: plane0 {thx,thy,thz,thx,thy,thz,1,1}, plane1 {tlx,tly,tlz,t2h,t2l,0,0,0}
// C/D (verified m74/m101): col=lane&31, row=(reg&3)+8*(reg>>2)+4*(lane>>5).
//
// R9 theory-driven changes vs R8 (pipes measured fully serialized, ~53us launch
// overhead):
//  - __launch_bounds__(512,2): 256-reg budget, 1 block/CU (R6 showed 1 block/CU
//    loses nothing vs 2). Full #pragma unroll on the mt loop so the scheduler
//    hoists the 8 ds_read_b128 per chunk and keeps MFMA results in arch VGPRs
//    (no AGPR split -> no v_accvgpr moves, fusable mins) = per-wave ILP.
//  - single cooperative launch with grid.sync() phases replaces 3 kernels
//    (prep -> main -> final serialization was ~half the wall clock).
// NOTE: fminf chains only (NO inline-asm v_min3: MFMA->VALU hazard, see R5->R6).
__global__ __launch_bounds__(TPB, 2) void mega(
    const float* __restrict__ pred, const float* __restrict__ tgt,
    const int* __restrict__ edges, char* __restrict__ ws,
    float* __restrict__ out)
{
    __shared__ __align__(16) char sB[2][2 * CHUNK * 16];   // 2 x 32 KB
    __shared__ float wred[WAVES];
    __shared__ int rowMin[ROWS_PER_BLOCK];
    double* sums = (double*)(ws + SUMS_OFF);
    const int lane = threadIdx.x & 63;
    const int wv = threadIdx.x >> 6;
    const int t = threadIdx.x;
    const int gid = blockIdx.x * TPB + threadIdx.x;        // 0..131071
    cg::grid_group grid = cg::this_grid();

    // ================= phase 0: fragment prep + zero sums =================
    if (gid < 6) sums[gid] = 0.0;
    if (gid < 2 * B_SZ * N_SZ) {
        const bool isTgt = gid < B_SZ * N_SZ;
        int row = isTgt ? gid : gid - B_SZ * N_SZ;         // 0..32767
        int batch = row >> 14, pt = row & (N_SZ - 1);
        const float* src = (isTgt ? tgt : pred) + (size_t)row * 3;
        char* base = ws + (isTgt ? 0 : DIR_FRAG_BYTES)
                        + (size_t)batch * BATCH_FRAG_BYTES;
        float tx = src[0], ty = src[1], tz = src[2];
        short hx = f2bf(tx), hy = f2bf(ty), hz = f2bf(tz);
        short lx = f2bf(tx - bf2f(hx)), ly = f2bf(ty - bf2f(hy)),
              lz = f2bf(tz - bf2f(hz));
        float t2 = fmaf(tx, tx, fmaf(ty, ty, tz * tz));
        short t2h = f2bf(t2), t2l = f2bf(t2 - bf2f(t2h));
        const short onep = 0x3f80;
        *(short8*)(base + (size_t)pt * 16) =
            (short8){hx, hy, hz, hx, hy, hz, onep, onep};
        *(short8*)(base + PLANE_BYTES + (size_t)pt * 16) =
            (short8){lx, ly, lz, t2h, t2l, 0, 0, 0};
    }
    grid.sync();

    // ================= phase 1a: edge loss (wave-level, fire-and-forget) ====
    if (gid < 2 * E_SZ) {                        // E_SZ % 64 == 0: wave-uniform b
        int b = gid >= E_SZ;
        int e = gid - b * E_SZ;
        int2 ee = ((const int2*)edges)[e];
        const float* p0 = pred + ((size_t)b * N_SZ + (size_t)ee.x) * 3;
        const float* p1 = pred + ((size_t)b * N_SZ + (size_t)ee.y) * 3;
        float dx = p0[0] - p1[0], dy = p0[1] - p1[1], dz = p0[2] - p1[2];
        float len = sqrtf(dx * dx + dy * dy + dz * dz);
        float s = len, q = len * len;
        for (int o = 32; o > 0; o >>= 1) {
            s += __shfl_down(s, o, 64);
            q += __shfl_down(q, o, 64);
        }
        if (lane == 0) {
            atomicAdd(&sums[2 + 2 * b], (double)s);
            atomicAdd(&sums[3 + 2 * b], (double)q);
        }
    }

    // ================= phase 1b: chamfer, rep = dir ========================
    const int bl = lane & 31;
    const int half = lane >> 5;
    const int rp = wv & 1;                    // row-pair: tiles 2rp,2rp+1
    const int cg_ = wv >> 1;                  // col-group: tiles [cg*8,cg*8+8)
    const int batch = blockIdx.x >> 7;
    const int rowInB = (blockIdx.x & 127) * ROWS_PER_BLOCK;
    const short one = 0x3f80;

    for (int rep = 0; rep < REPS; rep++) {
        const int dir = rep;                  // 0: rows=pred, search tgt
        const float* P = dir ? tgt : pred;
        const char* fragBase = ws + (size_t)dir * DIR_FRAG_BYTES
                                  + (size_t)batch * BATCH_FRAG_BYTES;

        auto stage = [&](int c, int buf) {
            const char* p0 = fragBase + (size_t)c * (CHUNK * 16);
            const char* p1 = fragBase + PLANE_BYTES + (size_t)c * (CHUNK * 16);
            char* d = sB[buf];
            gload_lds16(p0 + (size_t)t * 16,         d + (size_t)t * 16);
            gload_lds16(p0 + (size_t)(t + TPB) * 16, d + (size_t)(t + TPB) * 16);
            gload_lds16(p1 + (size_t)t * 16,         d + (size_t)(t + 2 * TPB) * 16);
            gload_lds16(p1 + (size_t)(t + TPB) * 16, d + (size_t)(t + 3 * TPB) * 16);
        };
        stage(0, 0);
        if (t < ROWS_PER_BLOCK) rowMin[t] = 0x7f7fffff;   // FLT_MAX bits

        // ---- A fragments for the wave's two row tiles ----
        short8 af[2];
        #pragma unroll
        for (int j = 0; j < 2; j++) {
            int r = batch * N_SZ + rowInB + rp * 64 + j * 32 + bl;
            const float* p = P + (size_t)r * 3;
            float px = p[0], py = p[1], pz = p[2];
            float ax = -2.f * px, ay = -2.f * py, az = -2.f * pz;
            short ahx = f2bf(ax), ahy = f2bf(ay), ahz = f2bf(az);
            short alx = f2bf(ax - bf2f(ahx)), aly = f2bf(ay - bf2f(ahy)),
                  alz = f2bf(az - bf2f(ahz));
            float p2 = fmaf(px, px, fmaf(py, py, pz * pz));
            short p2h = f2bf(p2), p2l = f2bf(p2 - bf2f(p2h));
            af[j] = half == 0
                ? (short8){ahx, ahy, ahz, alx, aly, alz, p2h, p2l}
                : (short8){ahx, ahy, ahz, one, one, 0, 0, 0};
        }

        float acc0[16], acc1[16];
        #pragma unroll
        for (int e = 0; e < 16; e++) { acc0[e] = FLT_MAX; acc1[e] = FLT_MAX; }
        const f32x16 zc = {0.f, 0.f, 0.f, 0.f, 0.f, 0.f, 0.f, 0.f,
                           0.f, 0.f, 0.f, 0.f, 0.f, 0.f, 0.f, 0.f};

        __syncthreads();

        for (int c = 0; c < NCHUNK; c++) {
            int buf = c & 1;
            if (c + 1 < NCHUNK) stage(c + 1, buf ^ 1);   // async, drains at barrier
            const char* bp = sB[buf] + half * (CHUNK * 16)
                           + (size_t)(cg_ * TILES_PER_CG * 32 + bl) * 16;
            #pragma unroll
            for (int mt = 0; mt < TILES_PER_CG; mt += 2) {
                short8 b0 = *(const short8*)(bp + (mt * 32) * 16);
                short8 b1 = *(const short8*)(bp + (mt * 32 + 32) * 16);
                {
                    f32x16 r0 = __builtin_amdgcn_mfma_f32_32x32x16_bf16(af[0], b0, zc, 0, 0, 0);
                    f32x16 r1 = __builtin_amdgcn_mfma_f32_32x32x16_bf16(af[0], b1, zc, 0, 0, 0);
                    #pragma unroll
                    for (int e = 0; e < 16; e++)
                        acc0[e] = fminf(fminf(r0[e], r1[e]), acc0[e]);
                }
                {
                    f32x16 r0 = __builtin_amdgcn_mfma_f32_32x32x16_bf16(af[1], b0, zc, 0, 0, 0);
                    f32x16 r1 = __builtin_amdgcn_mfma_f32_32x32x16_bf16(af[1], b1, zc, 0, 0, 0);
                    #pragma unroll
                    for (int e = 0; e < 16; e++)
                        acc1[e] = fminf(fminf(r0[e], r1[e]), acc1[e]);
                }
            }
            __syncthreads();
        }

        // ---- fold 32 col-lanes, publish per-row minima via LDS atomicMin ----
        #pragma unroll
        for (int j = 0; j < 2; j++) {
            #pragma unroll
            for (int e = 0; e < 16; e++) {
                float v = (j == 0) ? acc0[e] : acc1[e];
                v = fminf(v, __shfl_xor(v, 1));
                v = fminf(v, __shfl_xor(v, 2));
                v = fminf(v, __shfl_xor(v, 4));
                v = fminf(v, __shfl_xor(v, 8));
                v = fminf(v, __shfl_xor(v, 16));
                if (bl == 0) {
                    int row = rp * 64 + j * 32 + (e & 3) + 8 * (e >> 2) + 4 * half;
                    atomicMin(&rowMin[row], __float_as_int(fmaxf(v, 0.f)));
                }
            }
        }
        __syncthreads();

        // ---- sqrt + block sum (rows live in threads 0..127 = waves 0,1) ----
        if (t < ROWS_PER_BLOCK) {
            float s = sqrtf(__int_as_float(rowMin[t]));
            #pragma unroll
            for (int o = 32; o > 0; o >>= 1) s += __shfl_down(s, o, 64);
            if (lane == 0) wred[wv] = s;
        }
        __syncthreads();
        if (t == 0) atomicAdd(&sums[dir], (double)(wred[0] + wred[1]));
    }

    // ================= phase 2: combine to the 3 outputs ===================
    grid.sync();
    if (blockIdx.x == 0 && threadIdx.x == 0) {
        double c = sums[0] / (double)(B_SZ * N_SZ) + sums[1] / (double)(B_SZ * N_SZ);
        double e = 0.0;
        #pragma unroll
        for (int b = 0; b < B_SZ; b++) {
            double s = sums[2 + 2 * b], q = sums[3 + 2 * b];
            e += (q - s * s / (double)E_SZ) / (double)(E_SZ - 1);
        }
        e *= (1.0 / B_SZ);
        double tot = 1.0 * c + 0.1 * e;
        out[0] = (float)tot;
        out[1] = (float)c;
        out[2] = (float)e;
    }
}

extern "C" void kernel_launch(void* const* d_in, const int* in_sizes, int n_in,
                              void* d_out, int out_size, void* d_ws, size_t ws_size,
                              hipStream_t stream) {
    const float* pred = (const float*)d_in[0];       // (B, N, 3) fp32
    const float* tgt  = (const float*)d_in[1];       // (B, M, 3) fp32
    const int* edges  = (const int*)d_in[2];         // (E, 2) int32 (harness-converted)
    float* out = (float*)d_out;
    char* ws = (char*)d_ws;                          // needs 2 MB + 48 B

    void* args[] = {(void*)&pred, (void*)&tgt, (void*)&edges, (void*)&ws, (void*)&out};
    hipLaunchCooperativeKernel((void*)mega, dim3(GRID), dim3(TPB), args, 0, stream);
}

// Round 4
// 137.101 us; speedup vs baseline: 1.7838x; 1.7838x over previous
//
#include <hip/hip_runtime.h>
#include <float.h>

// Problem constants (from reference setup_inputs)
#define B_SZ 2
#define N_SZ 16384                  // N == M
#define E_SZ 49152

#define TPB 512
#define WAVES (TPB / 64)            // 8
#define ROWS_PER_BLOCK 128          // 4 row-tiles, ALL owned by every wave
#define CHUNK 1024                  // target points per LDS chunk
#define NCHUNK (N_SZ / CHUNK)       // 16
#define TILES_PER_CHUNK (CHUNK / 32) // 32
#define NCG 8                       // 8 col-groups = 8 waves
#define TILES_PER_CG (TILES_PER_CHUNK / NCG) // 4 col-tiles per col-group

#define CH_BLOCKS_PER_DIR (B_SZ * N_SZ / ROWS_PER_BLOCK)  // 256
#define CH_BLOCKS (2 * CH_BLOCKS_PER_DIR)                 // 512
#define EDGE_BLOCKS (B_SZ * E_SZ / TPB)                   // 192

// frag workspace: per dir, per batch: plane0 [16384 x 16B] then plane1
#define PLANE_BYTES (N_SZ * 16)                 // 256 KB
#define BATCH_FRAG_BYTES (2 * PLANE_BYTES)      // 512 KB
#define DIR_FRAG_BYTES (B_SZ * BATCH_FRAG_BYTES) // 1 MB
#define SUMS_OFF (2 * DIR_FRAG_BYTES)           // 2 MB

typedef short short8 __attribute__((ext_vector_type(8)));
typedef float f32x16 __attribute__((ext_vector_type(16)));

// ---- bf16 bit helpers (RNE); inputs are finite Gaussians ----
__device__ inline short f2bf(float f) {
    unsigned u = __float_as_uint(f);
    unsigned r = (u + 0x7fffu + ((u >> 16) & 1u)) >> 16;
    return (short)r;
}
__device__ inline float bf2f(short s) {
    return __uint_as_float(((unsigned)(unsigned short)s) << 16);
}

// ---- async global->LDS 16B per lane (CK-style addrspace casts) ----
typedef __attribute__((address_space(1))) const unsigned int g_u32;
typedef __attribute__((address_space(3))) unsigned int l_u32;
__device__ inline void gload_lds16(const void* g, void* l) {
    __builtin_amdgcn_global_load_lds((g_u32*)g, (l_u32*)l, 16, 0, 0);
}

// ---- prep: convert every point to B-operand fragments + zero sums ----
// B-rep per point t (search-set role):
//   plane0 (k0-7):  {thx,thy,thz, thx,thy,thz, 1, 1}
//   plane1 (k8-15): {tlx,tly,tlz, t2h,t2l, 0,0,0}
// idx 0..32767: tgt points -> dir0 buffer; 32768..65535: pred -> dir1 buffer.
__global__ __launch_bounds__(TPB) void prep(const float* __restrict__ pred,
                                            const float* __restrict__ tgt,
                                            char* __restrict__ ws) {
    int idx = blockIdx.x * TPB + threadIdx.x;       // 0..65535
    double* sums = (double*)(ws + SUMS_OFF);
    if (blockIdx.x == 0 && threadIdx.x < 6) sums[threadIdx.x] = 0.0;

    const bool isTgt = idx < B_SZ * N_SZ;
    int row = isTgt ? idx : idx - B_SZ * N_SZ;      // 0..32767
    int batch = row >> 14, pt = row & (N_SZ - 1);
    const float* src = (isTgt ? tgt : pred) + (size_t)row * 3;
    char* base = ws + (isTgt ? 0 : DIR_FRAG_BYTES) + (size_t)batch * BATCH_FRAG_BYTES;

    float tx = src[0], ty = src[1], tz = src[2];
    short hx = f2bf(tx), hy = f2bf(ty), hz = f2bf(tz);
    short lx = f2bf(tx - bf2f(hx)), ly = f2bf(ty - bf2f(hy)), lz = f2bf(tz - bf2f(hz));
    float t2 = fmaf(tx, tx, fmaf(ty, ty, tz * tz));
    short t2h = f2bf(t2), t2l = f2bf(t2 - bf2f(t2h));
    const short one = 0x3f80;

    *(short8*)(base + (size_t)pt * 16) = (short8){hx, hy, hz, hx, hy, hz, one, one};
    *(short8*)(base + PLANE_BYTES + (size_t)pt * 16) =
        (short8){lx, ly, lz, t2h, t2l, 0, 0, 0};
}

// ---- main: chamfer (both directions) + edge ----
// d^2 = (-2p).t + p^2 + t^2 via K=13 bf16 hi/lo split in ONE 32x32x16 MFMA.
// A lane: m=lane&31, k=(lane>>5)*8+j:
//   half0 (k0-7):  {ahx,ahy,ahz, alx,aly,alz, p2h,p2l}   (a = -2p)
//   half1 (k8-15): {ahx,ahy,ahz, 1, 1, 0,0,0}
// C/D (verified m74/m101): col=lane&31, row=(reg&3)+8*(reg>>2)+4*(lane>>5).
//
// R10 (theory: R8 = serial MFMA-wait + accvgpr copies + unfused mins + LDS):
//  - 4 A-tiles per wave (every wave owns ALL 128 block rows; waves split cols
//    into 8 col-groups) -> 2 ds_read_b128 feed 8 MFMAs (LDS reads halved).
//  - __launch_bounds__(512,2): ~256-reg budget so MFMA results stay in arch
//    VGPRs (min3 fusion, no v_accvgpr moves). Straight-line 4 j-blocks keep
//    nominal live results at 2x f32x16; mt loop is unroll 1 with explicit
//    next-pair prefetch (R9 lesson: NEVER fully unroll the chunk loop).
//  - 1 block/CU occupancy (R6/R8 showed 1 vs 2 blocks/CU is neutral).
// NOTE: fminf chains only (NO inline-asm v_min3: MFMA->VALU hazard, see R5->R6).
#define PROC(AF, ACC)                                                          \
    do {                                                                       \
        f32x16 r0 = __builtin_amdgcn_mfma_f32_32x32x16_bf16(AF, b0, zc, 0, 0, 0); \
        f32x16 r1 = __builtin_amdgcn_mfma_f32_32x32x16_bf16(AF, b1, zc, 0, 0, 0); \
        _Pragma("unroll")                                                      \
        for (int e = 0; e < 16; e++)                                           \
            ACC[e] = fminf(fminf(r0[e], r1[e]), ACC[e]);                       \
    } while (0)

__global__ __launch_bounds__(TPB, 2) void main_kernel(
    const float* __restrict__ pred, const float* __restrict__ tgt,
    const int* __restrict__ edges, char* __restrict__ ws)
{
    __shared__ __align__(16) char sB[2][2 * CHUNK * 16];   // 2 x 32 KB
    __shared__ float wred[WAVES], wred2[WAVES];
    __shared__ int rowMin[ROWS_PER_BLOCK];
    double* sums = (double*)(ws + SUMS_OFF);
    const int lane = threadIdx.x & 63;
    const int wv = threadIdx.x >> 6;
    const int t = threadIdx.x;

    if (blockIdx.x < CH_BLOCKS) {
        const int dir = blockIdx.x >> 8;          // 0: rows=pred, search tgt
        const int xb = blockIdx.x & 255;
        const int batch = xb >> 7;
        const int rowInB = (xb & 127) * ROWS_PER_BLOCK;
        const float* P = dir ? tgt : pred;
        const char* fragBase = ws + (size_t)dir * DIR_FRAG_BYTES
                                  + (size_t)batch * BATCH_FRAG_BYTES;
        const int bl = lane & 31;
        const int half = lane >> 5;
        const int cg = wv;                        // col-group: 4 tiles each

        auto stage = [&](int c, int buf) {
            const char* p0 = fragBase + (size_t)c * (CHUNK * 16);
            const char* p1 = fragBase + PLANE_BYTES + (size_t)c * (CHUNK * 16);
            char* d = sB[buf];
            gload_lds16(p0 + (size_t)t * 16,         d + (size_t)t * 16);
            gload_lds16(p0 + (size_t)(t + TPB) * 16, d + (size_t)(t + TPB) * 16);
            gload_lds16(p1 + (size_t)t * 16,         d + (size_t)(t + 2 * TPB) * 16);
            gload_lds16(p1 + (size_t)(t + TPB) * 16, d + (size_t)(t + 3 * TPB) * 16);
        };
        stage(0, 0);
        if (t < ROWS_PER_BLOCK) rowMin[t] = 0x7f7fffff;   // FLT_MAX bits

        // ---- A fragments: the wave's FOUR row tiles (= the whole block) ----
        const short one = 0x3f80;
        short8 af[4];
        #pragma unroll
        for (int j = 0; j < 4; j++) {
            int r = batch * N_SZ + rowInB + j * 32 + bl;
            const float* p = P + (size_t)r * 3;
            float px = p[0], py = p[1], pz = p[2];
            float ax = -2.f * px, ay = -2.f * py, az = -2.f * pz;
            short ahx = f2bf(ax), ahy = f2bf(ay), ahz = f2bf(az);
            short alx = f2bf(ax - bf2f(ahx)), aly = f2bf(ay - bf2f(ahy)),
                  alz = f2bf(az - bf2f(ahz));
            float p2 = fmaf(px, px, fmaf(py, py, pz * pz));
            short p2h = f2bf(p2), p2l = f2bf(p2 - bf2f(p2h));
            af[j] = half == 0
                ? (short8){ahx, ahy, ahz, alx, aly, alz, p2h, p2l}
                : (short8){ahx, ahy, ahz, one, one, 0, 0, 0};
        }

        float accA[16], accB[16], accC[16], accD[16];
        #pragma unroll
        for (int e = 0; e < 16; e++) {
            accA[e] = FLT_MAX; accB[e] = FLT_MAX;
            accC[e] = FLT_MAX; accD[e] = FLT_MAX;
        }
        const f32x16 zc = {0.f, 0.f, 0.f, 0.f, 0.f, 0.f, 0.f, 0.f,
                           0.f, 0.f, 0.f, 0.f, 0.f, 0.f, 0.f, 0.f};

        __syncthreads();

        for (int c = 0; c < NCHUNK; c++) {
            int buf = c & 1;
            if (c + 1 < NCHUNK) stage(c + 1, buf ^ 1);   // async, drains at barrier
            const char* bp = sB[buf] + half * (CHUNK * 16)
                           + (size_t)(cg * TILES_PER_CG * 32 + bl) * 16;
            short8 nb0 = *(const short8*)(bp + 0);
            short8 nb1 = *(const short8*)(bp + 512);     // 32*16
            #pragma unroll 1
            for (int mt = 0; mt < TILES_PER_CG; mt += 2) {
                short8 b0 = nb0, b1 = nb1;
                if (mt + 2 < TILES_PER_CG) {
                    nb0 = *(const short8*)(bp + (mt + 2) * 512);
                    nb1 = *(const short8*)(bp + (mt + 3) * 512);
                }
                PROC(af[0], accA);
                PROC(af[1], accB);
                PROC(af[2], accC);
                PROC(af[3], accD);
            }
            __syncthreads();
        }

        // ---- fold 32 col-lanes, publish per-row minima via LDS atomicMin ----
        #define FOLD(ACC, J)                                                    \
            do {                                                                \
                _Pragma("unroll")                                               \
                for (int e = 0; e < 16; e++) {                                  \
                    float v = ACC[e];                                           \
                    v = fminf(v, __shfl_xor(v, 1));                             \
                    v = fminf(v, __shfl_xor(v, 2));                             \
                    v = fminf(v, __shfl_xor(v, 4));                             \
                    v = fminf(v, __shfl_xor(v, 8));                             \
                    v = fminf(v, __shfl_xor(v, 16));                            \
                    if (bl == 0) {                                              \
                        int row = (J) * 32 + (e & 3) + 8 * (e >> 2) + 4 * half; \
                        atomicMin(&rowMin[row], __float_as_int(fmaxf(v, 0.f))); \
                    }                                                           \
                }                                                               \
            } while (0)
        FOLD(accA, 0);
        FOLD(accB, 1);
        FOLD(accC, 2);
        FOLD(accD, 3);
        __syncthreads();

        // ---- sqrt + block sum (rows live in threads 0..127 = waves 0,1) ----
        if (t < ROWS_PER_BLOCK) {
            float s = sqrtf(__int_as_float(rowMin[t]));
            #pragma unroll
            for (int o = 32; o > 0; o >>= 1) s += __shfl_down(s, o, 64);
            if (lane == 0) wred[wv] = s;
        }
        __syncthreads();
        if (t == 0) atomicAdd(&sums[dir], (double)(wred[0] + wred[1]));
    } else {
        // ---- edge loss (int32 edges per harness convention) ----
        int idx = (blockIdx.x - CH_BLOCKS) * TPB + threadIdx.x;  // 0..98303
        int b = idx >= E_SZ;                        // block-uniform (96 blocks/b)
        int e = idx - b * E_SZ;
        int2 ee = ((const int2*)edges)[e];
        const float* p0 = pred + ((size_t)b * N_SZ + (size_t)ee.x) * 3;
        const float* p1 = pred + ((size_t)b * N_SZ + (size_t)ee.y) * 3;
        float dx = p0[0] - p1[0], dy = p0[1] - p1[1], dz = p0[2] - p1[2];
        float len = sqrtf(dx * dx + dy * dy + dz * dz);
        float s = len, q = len * len;
        for (int o = 32; o > 0; o >>= 1) {
            s += __shfl_down(s, o, 64);
            q += __shfl_down(q, o, 64);
        }
        if (lane == 0) { wred[wv] = s; wred2[wv] = q; }
        __syncthreads();
        if (threadIdx.x == 0) {
            float ts = 0.f, tq = 0.f;
            #pragma unroll
            for (int w = 0; w < WAVES; w++) { ts += wred[w]; tq += wred2[w]; }
            atomicAdd(&sums[2 + 2 * b], (double)ts);
            atomicAdd(&sums[3 + 2 * b], (double)tq);
        }
    }
}

// ---- combine to the 3 outputs ----
__global__ void final_kernel(const char* __restrict__ ws, float* __restrict__ out) {
    const double* sums = (const double*)(ws + SUMS_OFF);
    double c = sums[0] / (double)(B_SZ * N_SZ) + sums[1] / (double)(B_SZ * N_SZ);
    double e = 0.0;
    #pragma unroll
    for (int b = 0; b < B_SZ; b++) {
        double s = sums[2 + 2 * b], q = sums[3 + 2 * b];
        e += (q - s * s / (double)E_SZ) / (double)(E_SZ - 1);
    }
    e *= (1.0 / B_SZ);
    double tot = 1.0 * c + 0.1 * e;
    out[0] = (float)tot;
    out[1] = (float)c;
    out[2] = (float)e;
}

extern "C" void kernel_launch(void* const* d_in, const int* in_sizes, int n_in,
                              void* d_out, int out_size, void* d_ws, size_t ws_size,
                              hipStream_t stream) {
    const float* pred = (const float*)d_in[0];       // (B, N, 3) fp32
    const float* tgt  = (const float*)d_in[1];       // (B, M, 3) fp32
    const int* edges  = (const int*)d_in[2];         // (E, 2) int32 (harness-converted)
    float* out = (float*)d_out;
    char* ws = (char*)d_ws;                          // needs 2 MB + 48 B

    // 1) convert points to MFMA B-fragments + zero sums
    prep<<<dim3((2 * B_SZ * N_SZ) / TPB), TPB, 0, stream>>>(pred, tgt, ws);

    // 2) chamfer (512 blocks, both dirs, complete row-mins) + edge (192 blocks)
    main_kernel<<<dim3(CH_BLOCKS + EDGE_BLOCKS), TPB, 0, stream>>>(
        pred, tgt, edges, ws);

    // 3) combine
    final_kernel<<<dim3(1), dim3(1), 0, stream>>>(ws, out);
}

// Round 5
// 106.030 us; speedup vs baseline: 2.3065x; 1.2930x over previous
//
#include <hip/hip_runtime.h>
#include <float.h>

// Problem constants (from reference setup_inputs)
#define B_SZ 2
#define N_SZ 16384                  // N == M
#define E_SZ 49152

#define TPB 512
#define WAVES (TPB / 64)            // 8
#define ROWS_PER_BLOCK 128          // 2 row-pairs x 64 rows; 4 col-groups
#define CHUNK 1024                  // target points per LDS chunk
#define NCHUNK (N_SZ / CHUNK)       // 16
#define TILES_PER_CHUNK (CHUNK / 32) // 32
#define TILES_PER_CG (TILES_PER_CHUNK / 4) // 8 col-tiles per col-group

#define CH_BLOCKS_PER_DIR (B_SZ * N_SZ / ROWS_PER_BLOCK)  // 256
#define CH_BLOCKS (2 * CH_BLOCKS_PER_DIR)                 // 512
#define EDGE_BLOCKS (B_SZ * E_SZ / TPB)                   // 192

// frag workspace: per dir, per batch: plane0 [16384 x 16B] then plane1
#define PLANE_BYTES (N_SZ * 16)                 // 256 KB
#define BATCH_FRAG_BYTES (2 * PLANE_BYTES)      // 512 KB
#define DIR_FRAG_BYTES (B_SZ * BATCH_FRAG_BYTES) // 1 MB
#define SUMS_OFF (2 * DIR_FRAG_BYTES)           // 2 MB

typedef short short8 __attribute__((ext_vector_type(8)));
typedef float f32x16 __attribute__((ext_vector_type(16)));

// ---- bf16 bit helpers (RNE); inputs are finite Gaussians ----
__device__ inline short f2bf(float f) {
    unsigned u = __float_as_uint(f);
    unsigned r = (u + 0x7fffu + ((u >> 16) & 1u)) >> 16;
    return (short)r;
}
__device__ inline float bf2f(short s) {
    return __uint_as_float(((unsigned)(unsigned short)s) << 16);
}

// ---- async global->LDS 16B per lane (CK-style addrspace casts) ----
typedef __attribute__((address_space(1))) const unsigned int g_u32;
typedef __attribute__((address_space(3))) unsigned int l_u32;
__device__ inline void gload_lds16(const void* g, void* l) {
    __builtin_amdgcn_global_load_lds((g_u32*)g, (l_u32*)l, 16, 0, 0);
}

// ---- prep: convert every point to B-operand fragments + zero sums ----
// B-rep per point t (search-set role):
//   plane0 (k0-7):  {thx,thy,thz, thx,thy,thz, 1, 1}
//   plane1 (k8-15): {tlx,tly,tlz, t2h,t2l, 0,0,0}
// idx 0..32767: tgt points -> dir0 buffer; 32768..65535: pred -> dir1 buffer.
__global__ __launch_bounds__(TPB) void prep(const float* __restrict__ pred,
                                            const float* __restrict__ tgt,
                                            char* __restrict__ ws) {
    int idx = blockIdx.x * TPB + threadIdx.x;       // 0..65535
    double* sums = (double*)(ws + SUMS_OFF);
    if (blockIdx.x == 0 && threadIdx.x < 6) sums[threadIdx.x] = 0.0;

    const bool isTgt = idx < B_SZ * N_SZ;
    int row = isTgt ? idx : idx - B_SZ * N_SZ;      // 0..32767
    int batch = row >> 14, pt = row & (N_SZ - 1);
    const float* src = (isTgt ? tgt : pred) + (size_t)row * 3;
    char* base = ws + (isTgt ? 0 : DIR_FRAG_BYTES) + (size_t)batch * BATCH_FRAG_BYTES;

    float tx = src[0], ty = src[1], tz = src[2];
    short hx = f2bf(tx), hy = f2bf(ty), hz = f2bf(tz);
    short lx = f2bf(tx - bf2f(hx)), ly = f2bf(ty - bf2f(hy)), lz = f2bf(tz - bf2f(hz));
    float t2 = fmaf(tx, tx, fmaf(ty, ty, tz * tz));
    short t2h = f2bf(t2), t2l = f2bf(t2 - bf2f(t2h));
    const short one = 0x3f80;

    *(short8*)(base + (size_t)pt * 16) = (short8){hx, hy, hz, hx, hy, hz, one, one};
    *(short8*)(base + PLANE_BYTES + (size_t)pt * 16) =
        (short8){lx, ly, lz, t2h, t2l, 0, 0, 0};
}

// ---- main: chamfer (both directions) + edge ----
// d^2 = (-2p).t + p^2 + t^2 via K=13 bf16 hi/lo split in ONE 32x32x16 MFMA.
// A lane: m=lane&31, k=(lane>>5)*8+j:
//   half0 (k0-7):  {ahx,ahy,ahz, alx,aly,alz, p2h,p2l}   (a = -2p)
//   half1 (k8-15): {ahx,ahy,ahz, 1, 1, 0,0,0}
// C/D (verified m74/m101): col=lane&31, row=(reg&3)+8*(reg>>2)+4*(lane>>5).
//
// R11 = R8 structure (best: 2 blocks/CU, 16 waves/CU) + asm v_min3 reduction.
// Counter evidence R6/R8/R10: VALUBusy*dur ~ 2-3x the min3 floor -> MFMA
// results were in AGPRs (v_accvgpr_read traffic) and/or fmin pairs unfused.
//  - "v"-constrained v_min3_f32 asm FORCES results+acc into arch VGPRs and
//    guarantees one min3 per element pair (VALU ~21us -> ~8us predicted).
//  - R5 hazard (asm consumer of builtin MFMA reads stale regs) is closed
//    DETERMINISTICALLY: a volatile 27-cycle s_nop fence asm takes the MFMA
//    results as operands (def-use pins MFMAs before it; volatile order pins
//    the min3 asms after it). 27 >= any documented MFMA->VALU hazard (<=18).
//  - reg budget: 32 acc + 32 results + af 8 + b 8 + misc ~ 100 <= 128 cap
//    of (512,4) -> keeps 2 blocks/CU, zero AGPRs. WRITE_SIZE = spill sentinel.
#define FENCE2(X0, X1)                                                         \
    asm volatile("s_nop 7\n\ts_nop 7\n\ts_nop 7\n\ts_nop 2"                    \
                 :: "v"(X0), "v"(X1))

#define MIN3G(ACC, X0, X1)                                                     \
    do {                                                                       \
        _Pragma("unroll")                                                      \
        for (int e_ = 0; e_ < 16; e_++)                                        \
            asm volatile("v_min3_f32 %0, %1, %2, %0"                           \
                         : "+v"(ACC[e_]) : "v"(X0[e_]), "v"(X1[e_]));          \
    } while (0)

#define PROC(AF, ACC)                                                          \
    do {                                                                       \
        f32x16 r0 = __builtin_amdgcn_mfma_f32_32x32x16_bf16(AF, b0, zc, 0, 0, 0); \
        f32x16 r1 = __builtin_amdgcn_mfma_f32_32x32x16_bf16(AF, b1, zc, 0, 0, 0); \
        FENCE2(r0, r1);                                                        \
        MIN3G(ACC, r0, r1);                                                    \
    } while (0)

__global__ __launch_bounds__(TPB, 4) void main_kernel(
    const float* __restrict__ pred, const float* __restrict__ tgt,
    const int* __restrict__ edges, char* __restrict__ ws)
{
    __shared__ __align__(16) char sB[2][2 * CHUNK * 16];   // 2 x 32 KB
    __shared__ float wred[WAVES], wred2[WAVES];
    __shared__ int rowMin[ROWS_PER_BLOCK];
    double* sums = (double*)(ws + SUMS_OFF);
    const int lane = threadIdx.x & 63;
    const int wv = threadIdx.x >> 6;
    const int t = threadIdx.x;

    if (blockIdx.x < CH_BLOCKS) {
        const int dir = blockIdx.x >> 8;          // 0: rows=pred, search tgt
        const int xb = blockIdx.x & 255;
        const int batch = xb >> 7;
        const int rowInB = (xb & 127) * ROWS_PER_BLOCK;
        const float* P = dir ? tgt : pred;
        const char* fragBase = ws + (size_t)dir * DIR_FRAG_BYTES
                                  + (size_t)batch * BATCH_FRAG_BYTES;
        const int bl = lane & 31;
        const int half = lane >> 5;
        const int rp = wv & 1;                    // row-pair: tiles 2rp,2rp+1
        const int cg = wv >> 1;                   // col-group: tiles [cg*8,cg*8+8)

        auto stage = [&](int c, int buf) {
            const char* p0 = fragBase + (size_t)c * (CHUNK * 16);
            const char* p1 = fragBase + PLANE_BYTES + (size_t)c * (CHUNK * 16);
            char* d = sB[buf];
            gload_lds16(p0 + (size_t)t * 16,         d + (size_t)t * 16);
            gload_lds16(p0 + (size_t)(t + TPB) * 16, d + (size_t)(t + TPB) * 16);
            gload_lds16(p1 + (size_t)t * 16,         d + (size_t)(t + 2 * TPB) * 16);
            gload_lds16(p1 + (size_t)(t + TPB) * 16, d + (size_t)(t + 3 * TPB) * 16);
        };
        stage(0, 0);
        if (t < ROWS_PER_BLOCK) rowMin[t] = 0x7f7fffff;   // FLT_MAX bits

        // ---- A fragments for the wave's two row tiles ----
        const short one = 0x3f80;
        short8 af[2];
        #pragma unroll
        for (int j = 0; j < 2; j++) {
            int r = batch * N_SZ + rowInB + rp * 64 + j * 32 + bl;
            const float* p = P + (size_t)r * 3;
            float px = p[0], py = p[1], pz = p[2];
            float ax = -2.f * px, ay = -2.f * py, az = -2.f * pz;
            short ahx = f2bf(ax), ahy = f2bf(ay), ahz = f2bf(az);
            short alx = f2bf(ax - bf2f(ahx)), aly = f2bf(ay - bf2f(ahy)),
                  alz = f2bf(az - bf2f(ahz));
            float p2 = fmaf(px, px, fmaf(py, py, pz * pz));
            short p2h = f2bf(p2), p2l = f2bf(p2 - bf2f(p2h));
            af[j] = half == 0
                ? (short8){ahx, ahy, ahz, alx, aly, alz, p2h, p2l}
                : (short8){ahx, ahy, ahz, one, one, 0, 0, 0};
        }

        float acc0[16], acc1[16];
        #pragma unroll
        for (int e = 0; e < 16; e++) { acc0[e] = FLT_MAX; acc1[e] = FLT_MAX; }
        const f32x16 zc = {0.f, 0.f, 0.f, 0.f, 0.f, 0.f, 0.f, 0.f,
                           0.f, 0.f, 0.f, 0.f, 0.f, 0.f, 0.f, 0.f};

        __syncthreads();

        for (int c = 0; c < NCHUNK; c++) {
            int buf = c & 1;
            if (c + 1 < NCHUNK) stage(c + 1, buf ^ 1);   // async, drains at barrier
            const char* bp = sB[buf] + half * (CHUNK * 16)
                           + (size_t)(cg * TILES_PER_CG * 32 + bl) * 16;
            #pragma unroll 1
            for (int mt = 0; mt < TILES_PER_CG; mt += 2) {
                short8 b0 = *(const short8*)(bp + (mt * 32) * 16);
                short8 b1 = *(const short8*)(bp + (mt * 32 + 32) * 16);
                PROC(af[0], acc0);
                PROC(af[1], acc1);
            }
            __syncthreads();
        }

        // ---- fold 32 col-lanes, publish per-row minima via LDS atomicMin ----
        #pragma unroll
        for (int j = 0; j < 2; j++) {
            #pragma unroll
            for (int e = 0; e < 16; e++) {
                float v = (j == 0) ? acc0[e] : acc1[e];
                v = fminf(v, __shfl_xor(v, 1));
                v = fminf(v, __shfl_xor(v, 2));
                v = fminf(v, __shfl_xor(v, 4));
                v = fminf(v, __shfl_xor(v, 8));
                v = fminf(v, __shfl_xor(v, 16));
                if (bl == 0) {
                    int row = rp * 64 + j * 32 + (e & 3) + 8 * (e >> 2) + 4 * half;
                    atomicMin(&rowMin[row], __float_as_int(fmaxf(v, 0.f)));
                }
            }
        }
        __syncthreads();

        // ---- sqrt + block sum (rows live in threads 0..127 = waves 0,1) ----
        if (t < ROWS_PER_BLOCK) {
            float s = sqrtf(__int_as_float(rowMin[t]));
            #pragma unroll
            for (int o = 32; o > 0; o >>= 1) s += __shfl_down(s, o, 64);
            if (lane == 0) wred[wv] = s;
        }
        __syncthreads();
        if (t == 0) atomicAdd(&sums[dir], (double)(wred[0] + wred[1]));
    } else {
        // ---- edge loss (int32 edges per harness convention) ----
        int idx = (blockIdx.x - CH_BLOCKS) * TPB + threadIdx.x;  // 0..98303
        int b = idx >= E_SZ;                        // block-uniform (96 blocks/b)
        int e = idx - b * E_SZ;
        int2 ee = ((const int2*)edges)[e];
        const float* p0 = pred + ((size_t)b * N_SZ + (size_t)ee.x) * 3;
        const float* p1 = pred + ((size_t)b * N_SZ + (size_t)ee.y) * 3;
        float dx = p0[0] - p1[0], dy = p0[1] - p1[1], dz = p0[2] - p1[2];
        float len = sqrtf(dx * dx + dy * dy + dz * dz);
        float s = len, q = len * len;
        for (int o = 32; o > 0; o >>= 1) {
            s += __shfl_down(s, o, 64);
            q += __shfl_down(q, o, 64);
        }
        if (lane == 0) { wred[wv] = s; wred2[wv] = q; }
        __syncthreads();
        if (threadIdx.x == 0) {
            float ts = 0.f, tq = 0.f;
            #pragma unroll
            for (int w = 0; w < WAVES; w++) { ts += wred[w]; tq += wred2[w]; }
            atomicAdd(&sums[2 + 2 * b], (double)ts);
            atomicAdd(&sums[3 + 2 * b], (double)tq);
        }
    }
}

// ---- combine to the 3 outputs ----
__global__ void final_kernel(const char* __restrict__ ws, float* __restrict__ out) {
    const double* sums = (const double*)(ws + SUMS_OFF);
    double c = sums[0] / (double)(B_SZ * N_SZ) + sums[1] / (double)(B_SZ * N_SZ);
    double e = 0.0;
    #pragma unroll
    for (int b = 0; b < B_SZ; b++) {
        double s = sums[2 + 2 * b], q = sums[3 + 2 * b];
        e += (q - s * s / (double)E_SZ) / (double)(E_SZ - 1);
    }
    e *= (1.0 / B_SZ);
    double tot = 1.0 * c + 0.1 * e;
    out[0] = (float)tot;
    out[1] = (float)c;
    out[2] = (float)e;
}

extern "C" void kernel_launch(void* const* d_in, const int* in_sizes, int n_in,
                              void* d_out, int out_size, void* d_ws, size_t ws_size,
                              hipStream_t stream) {
    const float* pred = (const float*)d_in[0];       // (B, N, 3) fp32
    const float* tgt  = (const float*)d_in[1];       // (B, M, 3) fp32
    const int* edges  = (const int*)d_in[2];         // (E, 2) int32 (harness-converted)
    float* out = (float*)d_out;
    char* ws = (char*)d_ws;                          // needs 2 MB + 48 B

    // 1) convert points to MFMA B-fragments + zero sums
    prep<<<dim3((2 * B_SZ * N_SZ) / TPB), TPB, 0, stream>>>(pred, tgt, ws);

    // 2) chamfer (512 blocks, both dirs, complete row-mins) + edge (192 blocks)
    main_kernel<<<dim3(CH_BLOCKS + EDGE_BLOCKS), TPB, 0, stream>>>(
        pred, tgt, edges, ws);

    // 3) combine
    final_kernel<<<dim3(1), dim3(1), 0, stream>>>(ws, out);
}

// Round 6
// 103.964 us; speedup vs baseline: 2.3524x; 1.0199x over previous
//
#include <hip/hip_runtime.h>
#include <float.h>

// Problem constants (from reference setup_inputs)
#define B_SZ 2
#define N_SZ 16384                  // N == M
#define E_SZ 49152

#define TPB 512
#define WAVES (TPB / 64)            // 8
#define ROWS_PER_BLOCK 128          // 2 row-pairs x 64 rows; 4 col-groups
#define NTILES (N_SZ / 32)          // 512 col-tiles per (dir,batch)
#define TILES_PER_CG (NTILES / 4)   // 128 tiles per col-group

#define CH_BLOCKS_PER_DIR (B_SZ * N_SZ / ROWS_PER_BLOCK)  // 256
#define CH_BLOCKS (2 * CH_BLOCKS_PER_DIR)                 // 512
#define EDGE_BLOCKS (B_SZ * E_SZ / TPB)                   // 192

// frag workspace: per dir, per batch: plane0 [16384 x 16B] then plane1
#define PLANE_BYTES (N_SZ * 16)                 // 256 KB
#define BATCH_FRAG_BYTES (2 * PLANE_BYTES)      // 512 KB
#define DIR_FRAG_BYTES (B_SZ * BATCH_FRAG_BYTES) // 1 MB
#define SUMS_OFF (2 * DIR_FRAG_BYTES)           // 2 MB

typedef short short8 __attribute__((ext_vector_type(8)));
typedef float f32x16 __attribute__((ext_vector_type(16)));

// ---- bf16 bit helpers (RNE); inputs are finite Gaussians ----
__device__ inline short f2bf(float f) {
    unsigned u = __float_as_uint(f);
    unsigned r = (u + 0x7fffu + ((u >> 16) & 1u)) >> 16;
    return (short)r;
}
__device__ inline float bf2f(short s) {
    return __uint_as_float(((unsigned)(unsigned short)s) << 16);
}

// ---- prep: convert every point to B-operand fragments + zero sums ----
// B-rep per point t (search-set role):
//   plane0 (k0-7):  {thx,thy,thz, thx,thy,thz, 1, 1}
//   plane1 (k8-15): {tlx,tly,tlz, t2h,t2l, 0,0,0}
// idx 0..32767: tgt points -> dir0 buffer; 32768..65535: pred -> dir1 buffer.
__global__ __launch_bounds__(TPB) void prep(const float* __restrict__ pred,
                                            const float* __restrict__ tgt,
                                            char* __restrict__ ws) {
    int idx = blockIdx.x * TPB + threadIdx.x;       // 0..65535
    double* sums = (double*)(ws + SUMS_OFF);
    if (blockIdx.x == 0 && threadIdx.x < 6) sums[threadIdx.x] = 0.0;

    const bool isTgt = idx < B_SZ * N_SZ;
    int row = isTgt ? idx : idx - B_SZ * N_SZ;      // 0..32767
    int batch = row >> 14, pt = row & (N_SZ - 1);
    const float* src = (isTgt ? tgt : pred) + (size_t)row * 3;
    char* base = ws + (isTgt ? 0 : DIR_FRAG_BYTES) + (size_t)batch * BATCH_FRAG_BYTES;

    float tx = src[0], ty = src[1], tz = src[2];
    short hx = f2bf(tx), hy = f2bf(ty), hz = f2bf(tz);
    short lx = f2bf(tx - bf2f(hx)), ly = f2bf(ty - bf2f(hy)), lz = f2bf(tz - bf2f(hz));
    float t2 = fmaf(tx, tx, fmaf(ty, ty, tz * tz));
    short t2h = f2bf(t2), t2l = f2bf(t2 - bf2f(t2h));
    const short one = 0x3f80;

    *(short8*)(base + (size_t)pt * 16) = (short8){hx, hy, hz, hx, hy, hz, one, one};
    *(short8*)(base + PLANE_BYTES + (size_t)pt * 16) =
        (short8){lx, ly, lz, t2h, t2l, 0, 0, 0};
}

// ---- main: chamfer (both directions) + edge ----
// d^2 = (-2p).t + p^2 + t^2 via K=13 bf16 hi/lo split in ONE 32x32x16 MFMA.
// A lane: m=lane&31, k=(lane>>5)*8+j:
//   half0 (k0-7):  {ahx,ahy,ahz, alx,aly,alz, p2h,p2l}   (a = -2p)
//   half1 (k8-15): {ahx,ahy,ahz, 1, 1, 0,0,0}
// C/D (verified m74/m101): col=lane&31, row=(reg&3)+8*(reg>>2)+4*(lane>>5).
//
// R12: NO LDS STAGING. B-panels (2 MB total) are L2-resident (FETCH_SIZE 10MB
// vs 256MB logical reads proved 96% L2 absorption). R6/R8/R11 all stuck at
// 46-52us with the chunk+barrier structure regardless of min-flavor/occupancy:
// the invariant cost was the LDS pipe + 16 vmcnt(0)-drain barriers. Now each
// wave streams its 128 col-tiles straight from global with an explicit
// 4-tile register prefetch pipeline; ZERO barriers in the K-loop.
//  - (512,2): 256-reg budget, 1 block/CU (R6 proved this costs nothing) ->
//    no 128-cap AGPR shuttle pathology (R10/R11 lesson).
//  - fminf chains only (R5/R6: asm consumers of MFMA hazard; R11: asm min3
//    bought nothing anyway). #pragma unroll 1 outer loop (R9 lesson).
__global__ __launch_bounds__(TPB, 2) void main_kernel(
    const float* __restrict__ pred, const float* __restrict__ tgt,
    const int* __restrict__ edges, char* __restrict__ ws)
{
    __shared__ float wred[WAVES], wred2[WAVES];
    __shared__ int rowMin[ROWS_PER_BLOCK];
    double* sums = (double*)(ws + SUMS_OFF);
    const int lane = threadIdx.x & 63;
    const int wv = threadIdx.x >> 6;
    const int t = threadIdx.x;

    if (blockIdx.x < CH_BLOCKS) {
        const int dir = blockIdx.x >> 8;          // 0: rows=pred, search tgt
        const int xb = blockIdx.x & 255;
        const int batch = xb >> 7;
        const int rowInB = (xb & 127) * ROWS_PER_BLOCK;
        const float* P = dir ? tgt : pred;
        const char* fragBase = ws + (size_t)dir * DIR_FRAG_BYTES
                                  + (size_t)batch * BATCH_FRAG_BYTES;
        const int bl = lane & 31;
        const int half = lane >> 5;
        const int rp = wv & 1;                    // row-pair: which 64 rows
        const int cg = wv >> 1;                   // col-group: 128 tiles each

        if (t < ROWS_PER_BLOCK) rowMin[t] = 0x7f7fffff;   // FLT_MAX bits

        // ---- A fragments for the wave's two row tiles ----
        const short one = 0x3f80;
        short8 af[2];
        #pragma unroll
        for (int j = 0; j < 2; j++) {
            int r = batch * N_SZ + rowInB + rp * 64 + j * 32 + bl;
            const float* p = P + (size_t)r * 3;
            float px = p[0], py = p[1], pz = p[2];
            float ax = -2.f * px, ay = -2.f * py, az = -2.f * pz;
            short ahx = f2bf(ax), ahy = f2bf(ay), ahz = f2bf(az);
            short alx = f2bf(ax - bf2f(ahx)), aly = f2bf(ay - bf2f(ahy)),
                  alz = f2bf(az - bf2f(ahz));
            float p2 = fmaf(px, px, fmaf(py, py, pz * pz));
            short p2h = f2bf(p2), p2l = f2bf(p2 - bf2f(p2h));
            af[j] = half == 0
                ? (short8){ahx, ahy, ahz, alx, aly, alz, p2h, p2l}
                : (short8){ahx, ahy, ahz, one, one, 0, 0, 0};
        }

        float acc0[16], acc1[16];
        #pragma unroll
        for (int e = 0; e < 16; e++) { acc0[e] = FLT_MAX; acc1[e] = FLT_MAX; }
        const f32x16 zc = {0.f, 0.f, 0.f, 0.f, 0.f, 0.f, 0.f, 0.f,
                           0.f, 0.f, 0.f, 0.f, 0.f, 0.f, 0.f, 0.f};

        // ---- B stream: this wave's 128 tiles, straight from global (L2) ----
        // lane's 16B for tile tc: fragBase + half*PLANE + (tc*32 + bl)*16
        const char* bbase = fragBase + (size_t)half * PLANE_BYTES
                                     + (size_t)bl * 16;
        const int tbase = cg * TILES_PER_CG;
        auto ldb = [&](int tc) {
            return *(const short8*)(bbase + (size_t)tc * 512);
        };

        #define DOPAIR(X0, X1)                                                 \
            do {                                                               \
                f32x16 r0 = __builtin_amdgcn_mfma_f32_32x32x16_bf16(af[0], X0, zc, 0, 0, 0); \
                f32x16 r1 = __builtin_amdgcn_mfma_f32_32x32x16_bf16(af[0], X1, zc, 0, 0, 0); \
                _Pragma("unroll")                                              \
                for (int e = 0; e < 16; e++)                                   \
                    acc0[e] = fminf(fminf(r0[e], r1[e]), acc0[e]);             \
                f32x16 s0 = __builtin_amdgcn_mfma_f32_32x32x16_bf16(af[1], X0, zc, 0, 0, 0); \
                f32x16 s1 = __builtin_amdgcn_mfma_f32_32x32x16_bf16(af[1], X1, zc, 0, 0, 0); \
                _Pragma("unroll")                                              \
                for (int e = 0; e < 16; e++)                                   \
                    acc1[e] = fminf(fminf(s0[e], s1[e]), acc1[e]);             \
            } while (0)

        short8 b0 = ldb(tbase + 0), b1 = ldb(tbase + 1);
        short8 b2 = ldb(tbase + 2), b3 = ldb(tbase + 3);
        __syncthreads();                          // rowMin init visible

        #pragma unroll 1
        for (int i = 0; i < TILES_PER_CG / 4; i++) {   // 32 iters x 4 tiles
            int pf = (i < TILES_PER_CG / 4 - 1) ? tbase + 4 * (i + 1) : tbase;
            {
                short8 x0 = b0, x1 = b1;
                b0 = ldb(pf + 0); b1 = ldb(pf + 1);    // prefetch, 1 iter ahead
                DOPAIR(x0, x1);
            }
            {
                short8 x0 = b2, x1 = b3;
                b2 = ldb(pf + 2); b3 = ldb(pf + 3);
                DOPAIR(x0, x1);
            }
        }

        // ---- fold 32 col-lanes, publish per-row minima via LDS atomicMin ----
        #pragma unroll
        for (int j = 0; j < 2; j++) {
            #pragma unroll
            for (int e = 0; e < 16; e++) {
                float v = (j == 0) ? acc0[e] : acc1[e];
                v = fminf(v, __shfl_xor(v, 1));
                v = fminf(v, __shfl_xor(v, 2));
                v = fminf(v, __shfl_xor(v, 4));
                v = fminf(v, __shfl_xor(v, 8));
                v = fminf(v, __shfl_xor(v, 16));
                if (bl == 0) {
                    int row = rp * 64 + j * 32 + (e & 3) + 8 * (e >> 2) + 4 * half;
                    atomicMin(&rowMin[row], __float_as_int(fmaxf(v, 0.f)));
                }
            }
        }
        __syncthreads();

        // ---- sqrt + block sum (rows live in threads 0..127 = waves 0,1) ----
        if (t < ROWS_PER_BLOCK) {
            float s = sqrtf(__int_as_float(rowMin[t]));
            #pragma unroll
            for (int o = 32; o > 0; o >>= 1) s += __shfl_down(s, o, 64);
            if (lane == 0) wred[wv] = s;
        }
        __syncthreads();
        if (t == 0) atomicAdd(&sums[dir], (double)(wred[0] + wred[1]));
    } else {
        // ---- edge loss (int32 edges per harness convention) ----
        int idx = (blockIdx.x - CH_BLOCKS) * TPB + threadIdx.x;  // 0..98303
        int b = idx >= E_SZ;                        // block-uniform (96 blocks/b)
        int e = idx - b * E_SZ;
        int2 ee = ((const int2*)edges)[e];
        const float* p0 = pred + ((size_t)b * N_SZ + (size_t)ee.x) * 3;
        const float* p1 = pred + ((size_t)b * N_SZ + (size_t)ee.y) * 3;
        float dx = p0[0] - p1[0], dy = p0[1] - p1[1], dz = p0[2] - p1[2];
        float len = sqrtf(dx * dx + dy * dy + dz * dz);
        float s = len, q = len * len;
        for (int o = 32; o > 0; o >>= 1) {
            s += __shfl_down(s, o, 64);
            q += __shfl_down(q, o, 64);
        }
        if (lane == 0) { wred[wv] = s; wred2[wv] = q; }
        __syncthreads();
        if (threadIdx.x == 0) {
            float ts = 0.f, tq = 0.f;
            #pragma unroll
            for (int w = 0; w < WAVES; w++) { ts += wred[w]; tq += wred2[w]; }
            atomicAdd(&sums[2 + 2 * b], (double)ts);
            atomicAdd(&sums[3 + 2 * b], (double)tq);
        }
    }
}

// ---- combine to the 3 outputs ----
__global__ void final_kernel(const char* __restrict__ ws, float* __restrict__ out) {
    const double* sums = (const double*)(ws + SUMS_OFF);
    double c = sums[0] / (double)(B_SZ * N_SZ) + sums[1] / (double)(B_SZ * N_SZ);
    double e = 0.0;
    #pragma unroll
    for (int b = 0; b < B_SZ; b++) {
        double s = sums[2 + 2 * b], q = sums[3 + 2 * b];
        e += (q - s * s / (double)E_SZ) / (double)(E_SZ - 1);
    }
    e *= (1.0 / B_SZ);
    double tot = 1.0 * c + 0.1 * e;
    out[0] = (float)tot;
    out[1] = (float)c;
    out[2] = (float)e;
}

extern "C" void kernel_launch(void* const* d_in, const int* in_sizes, int n_in,
                              void* d_out, int out_size, void* d_ws, size_t ws_size,
                              hipStream_t stream) {
    const float* pred = (const float*)d_in[0];       // (B, N, 3) fp32
    const float* tgt  = (const float*)d_in[1];       // (B, M, 3) fp32
    const int* edges  = (const int*)d_in[2];         // (E, 2) int32 (harness-converted)
    float* out = (float*)d_out;
    char* ws = (char*)d_ws;                          // needs 2 MB + 48 B

    // 1) convert points to MFMA B-fragments + zero sums
    prep<<<dim3((2 * B_SZ * N_SZ) / TPB), TPB, 0, stream>>>(pred, tgt, ws);

    // 2) chamfer (512 blocks, both dirs, complete row-mins) + edge (192 blocks)
    main_kernel<<<dim3(CH_BLOCKS + EDGE_BLOCKS), TPB, 0, stream>>>(
        pred, tgt, edges, ws);

    // 3) combine
    final_kernel<<<dim3(1), dim3(1), 0, stream>>>(ws, out);
}